// Round 1
// baseline (617.454 us; speedup 1.0000x reference)
//
#include <hip/hip_runtime.h>
#include <stdint.h>

#define M_DIM 8192
#define N_DIM 4096
#define K_DIM 4096
#define BM 128
#define BN 128
#define BK 32

typedef __bf16 bf16x8 __attribute__((ext_vector_type(8)));
typedef float f32x4 __attribute__((ext_vector_type(4)));
typedef unsigned short u16x4 __attribute__((ext_vector_type(4)));

__device__ __forceinline__ unsigned short f2bf(float f) {
    // round-to-nearest-even fp32 -> bf16 (no NaN handling needed for this data)
    unsigned int u = __builtin_bit_cast(unsigned int, f);
    u += 0x7fffu + ((u >> 16) & 1u);
    return (unsigned short)(u >> 16);
}

__device__ __forceinline__ void async_copy16(const void* g, void* l) {
    __builtin_amdgcn_global_load_lds(
        (const __attribute__((address_space(1))) void*)g,
        (__attribute__((address_space(3))) void*)l, 16, 0, 0);
}

// ---- pass 1: sum(|w|) into a double accumulator ----
__global__ void abssum_kernel(const float4* __restrict__ w, double* __restrict__ acc, int n4) {
    int tid = blockIdx.x * blockDim.x + threadIdx.x;
    int stride = gridDim.x * blockDim.x;
    float s = 0.f;
    for (int i = tid; i < n4; i += stride) {
        float4 v = w[i];
        s += fabsf(v.x) + fabsf(v.y) + fabsf(v.z) + fabsf(v.w);
    }
    double d = (double)s;
    #pragma unroll
    for (int off = 32; off > 0; off >>= 1) d += __shfl_down(d, off, 64);
    if ((threadIdx.x & 63) == 0) atomicAdd(acc, d);
}

// ---- pass 2: quantize weight to ternary, store as bf16 bits ----
__global__ void quant_kernel(const float4* __restrict__ w, u16x4* __restrict__ qw,
                             const double* __restrict__ acc, int n4) {
    float gamma = (float)(*acc * (1.0 / 16777216.0));  // mean |w| over 4096*4096
    gamma = fmaxf(gamma, 1e-8f);
    int i = blockIdx.x * blockDim.x + threadIdx.x;
    if (i >= n4) return;
    float4 v = w[i];
    u16x4 o;
    o.x = f2bf(fminf(fmaxf(rintf(v.x / gamma), -1.f), 1.f));
    o.y = f2bf(fminf(fmaxf(rintf(v.y / gamma), -1.f), 1.f));
    o.z = f2bf(fminf(fmaxf(rintf(v.z / gamma), -1.f), 1.f));
    o.w = f2bf(fminf(fmaxf(rintf(v.w / gamma), -1.f), 1.f));
    qw[i] = o;
}

// ---- pass 3: x fp32 -> bf16 ----
__global__ void cvt_kernel(const float4* __restrict__ x, u16x4* __restrict__ xb, int n4) {
    int i = blockIdx.x * blockDim.x + threadIdx.x;
    if (i >= n4) return;
    float4 v = x[i];
    u16x4 o;
    o.x = f2bf(v.x); o.y = f2bf(v.y); o.z = f2bf(v.z); o.w = f2bf(v.w);
    xb[i] = o;
}

// ---- pass 4: C[M,N] = Xb[M,K] @ Qw[N,K]^T + bias, bf16 MFMA, fp32 out ----
__global__ __launch_bounds__(256) void gemm_kernel(
    const unsigned short* __restrict__ xb,   // [M,K] bf16 bits
    const unsigned short* __restrict__ qw,   // [N,K] bf16 bits
    const float* __restrict__ bias,          // [N]
    float* __restrict__ out)                 // [M,N] fp32
{
    __shared__ __align__(16) unsigned short As[BM * BK];  // 8 KB
    __shared__ __align__(16) unsigned short Bs[BN * BK];  // 8 KB

    const int tid  = threadIdx.x;
    const int wave = tid >> 6;
    const int lane = tid & 63;
    const int wm   = (wave >> 1) * 64;   // wave's m-offset within tile
    const int wn   = (wave & 1) * 64;    // wave's n-offset within tile
    const int lm   = lane & 15;
    const int quad = lane >> 4;

    const int bm = blockIdx.y * BM;
    const int bn = blockIdx.x * BN;

    // staging: 8 segments of 16 rows x 64B; wave w stages segments 2w, 2w+1.
    // global_load_lds: LDS dest = wave-uniform base + lane*16 -> exactly
    // row-major [128][32] bf16 when lane l covers row l/4, bytes (l%4)*16.
    const int s0 = wave * 2;
    const int srow0 = s0 * 16 + (lane >> 2);
    const int srow1 = srow0 + 16;
    const int scol  = (lane & 3) * 8;   // bf16 elements

    const unsigned short* gA0 = xb + (size_t)(bm + srow0) * K_DIM + scol;
    const unsigned short* gA1 = xb + (size_t)(bm + srow1) * K_DIM + scol;
    const unsigned short* gB0 = qw + (size_t)(bn + srow0) * K_DIM + scol;
    const unsigned short* gB1 = qw + (size_t)(bn + srow1) * K_DIM + scol;

    unsigned short* lA0 = &As[(size_t)s0 * 512];        // 512 ushort = 1024B/segment
    unsigned short* lA1 = &As[(size_t)(s0 + 1) * 512];
    unsigned short* lB0 = &Bs[(size_t)s0 * 512];
    unsigned short* lB1 = &Bs[(size_t)(s0 + 1) * 512];

    f32x4 acc[4][4];
    #pragma unroll
    for (int i = 0; i < 4; i++)
        #pragma unroll
        for (int j = 0; j < 4; j++) acc[i][j] = (f32x4){0.f, 0.f, 0.f, 0.f};

    for (int kt = 0; kt < K_DIM; kt += BK) {
        async_copy16(gA0 + kt, lA0);
        async_copy16(gA1 + kt, lA1);
        async_copy16(gB0 + kt, lB0);
        async_copy16(gB1 + kt, lB1);
        __syncthreads();   // drains vmcnt -> staged data visible

        bf16x8 a[4], b[4];
        #pragma unroll
        for (int mi = 0; mi < 4; mi++)
            a[mi] = *(const bf16x8*)&As[(wm + mi * 16 + lm) * BK + quad * 8];
        #pragma unroll
        for (int ni = 0; ni < 4; ni++)
            b[ni] = *(const bf16x8*)&Bs[(wn + ni * 16 + lm) * BK + quad * 8];

        #pragma unroll
        for (int mi = 0; mi < 4; mi++)
            #pragma unroll
            for (int ni = 0; ni < 4; ni++)
                acc[mi][ni] = __builtin_amdgcn_mfma_f32_16x16x32_bf16(
                    a[mi], b[ni], acc[mi][ni], 0, 0, 0);

        __syncthreads();   // all reads done before next overwrite
    }

    // epilogue: C/D layout col=lane&15, row=quad*4+reg (m89/m91-verified)
    float bl[4];
    #pragma unroll
    for (int ni = 0; ni < 4; ni++) bl[ni] = bias[bn + wn + ni * 16 + lm];

    #pragma unroll
    for (int mi = 0; mi < 4; mi++) {
        #pragma unroll
        for (int r = 0; r < 4; r++) {
            const int grow = bm + wm + mi * 16 + quad * 4 + r;
            float* orow = out + (size_t)grow * N_DIM + bn;
            #pragma unroll
            for (int ni = 0; ni < 4; ni++)
                orow[wn + ni * 16 + lm] = acc[mi][ni][r] + bl[ni];
        }
    }
}

extern "C" void kernel_launch(void* const* d_in, const int* in_sizes, int n_in,
                              void* d_out, int out_size, void* d_ws, size_t ws_size,
                              hipStream_t stream) {
    const float* x    = (const float*)d_in[0];   // [4,2048,4096]
    const float* w    = (const float*)d_in[1];   // [4096,4096]
    const float* bias = (const float*)d_in[2];   // [4096]
    float* out = (float*)d_out;

    char* ws = (char*)d_ws;
    unsigned short* xb = (unsigned short*)ws;                                   // 64 MB
    unsigned short* qw = (unsigned short*)(ws + (size_t)M_DIM * K_DIM * 2);     // 32 MB
    double* gacc = (double*)(ws + (size_t)M_DIM * K_DIM * 2 + (size_t)N_DIM * K_DIM * 2);

    hipMemsetAsync(gacc, 0, sizeof(double), stream);

    const int wn4 = (N_DIM * K_DIM) / 4;   // 4.19M float4
    const int xn4 = (M_DIM * K_DIM) / 4;   // 8.39M float4

    abssum_kernel<<<1024, 256, 0, stream>>>((const float4*)w, gacc, wn4);
    quant_kernel<<<(wn4 + 255) / 256, 256, 0, stream>>>((const float4*)w, (u16x4*)qw, gacc, wn4);
    cvt_kernel<<<(xn4 + 255) / 256, 256, 0, stream>>>((const float4*)x, (u16x4*)xb, xn4);

    dim3 grid(N_DIM / BN, M_DIM / BM);   // (32, 64)
    gemm_kernel<<<grid, 256, 0, stream>>>(xb, qw, bias, out);
}

// Round 2
// 428.913 us; speedup vs baseline: 1.4396x; 1.4396x over previous
//
#include <hip/hip_runtime.h>
#include <stdint.h>

#define M_DIM 8192
#define N_DIM 4096
#define K_DIM 4096
#define BM 128
#define BN 128
#define BK 64   // i8 elements per K-tile = 64 bytes/row, same staging bytes as bf16 BK=32

typedef int i32x4 __attribute__((ext_vector_type(4)));
typedef float f32x4 __attribute__((ext_vector_type(4)));

__device__ __forceinline__ void async_copy16(const void* g, void* l) {
    __builtin_amdgcn_global_load_lds(
        (const __attribute__((address_space(1))) void*)g,
        (__attribute__((address_space(3))) void*)l, 16, 0, 0);
}

// ---- pass 1: per-block partial sums of |w| (deterministic, no atomics) ----
__global__ __launch_bounds__(256) void abssum_partial(const float4* __restrict__ w,
                                                      double* __restrict__ partials) {
    // 1024 blocks x 4096 float4 each (contiguous chunk -> deterministic order)
    const int lane = threadIdx.x & 63;
    const int wave = threadIdx.x >> 6;
    int base = blockIdx.x * 4096 + threadIdx.x;
    float s = 0.f;
    #pragma unroll
    for (int i = 0; i < 16; i++) {
        float4 v = w[base + i * 256];
        s += fabsf(v.x) + fabsf(v.y) + fabsf(v.z) + fabsf(v.w);
    }
    double d = (double)s;
    #pragma unroll
    for (int off = 32; off > 0; off >>= 1) d += __shfl_down(d, off, 64);
    __shared__ double wsum[4];
    if (lane == 0) wsum[wave] = d;
    __syncthreads();
    if (threadIdx.x == 0)
        partials[blockIdx.x] = (wsum[0] + wsum[1]) + (wsum[2] + wsum[3]);
}

// ---- pass 2: reduce 1024 partials -> gamma (single block, deterministic) ----
__global__ __launch_bounds__(256) void gamma_reduce(const double* __restrict__ partials,
                                                    float* __restrict__ gamma_out) {
    const int lane = threadIdx.x & 63;
    const int wave = threadIdx.x >> 6;
    double d = partials[threadIdx.x] + partials[threadIdx.x + 256] +
               partials[threadIdx.x + 512] + partials[threadIdx.x + 768];
    #pragma unroll
    for (int off = 32; off > 0; off >>= 1) d += __shfl_down(d, off, 64);
    __shared__ double wsum[4];
    if (lane == 0) wsum[wave] = d;
    __syncthreads();
    if (threadIdx.x == 0) {
        double total = (wsum[0] + wsum[1]) + (wsum[2] + wsum[3]);
        float g = (float)(total * (1.0 / 16777216.0));  // mean |w| over 4096*4096
        gamma_out[0] = fmaxf(g, 1e-8f);
    }
}

// ---- pass 3: quantize weight to ternary i8 ----
__global__ __launch_bounds__(256) void wquant(const float4* __restrict__ w,
                                              char4* __restrict__ qw,
                                              const float* __restrict__ gamma_p, int n4) {
    float gamma = gamma_p[0];
    int i = blockIdx.x * blockDim.x + threadIdx.x;
    if (i >= n4) return;
    float4 v = w[i];
    char4 o;
    // true division (matches np fp32 semantics at the 0.5 rounding boundary)
    o.x = (signed char)fminf(fmaxf(rintf(v.x / gamma), -1.f), 1.f);
    o.y = (signed char)fminf(fmaxf(rintf(v.y / gamma), -1.f), 1.f);
    o.z = (signed char)fminf(fmaxf(rintf(v.z / gamma), -1.f), 1.f);
    o.w = (signed char)fminf(fmaxf(rintf(v.w / gamma), -1.f), 1.f);
    qw[i] = o;
}

// ---- pass 4: per-row absmax + quantize x to i8 (one block per row) ----
__global__ __launch_bounds__(256) void xquant(const float* __restrict__ x,
                                              char* __restrict__ xq,
                                              float* __restrict__ xscale) {
    const int row = blockIdx.x;
    const int lane = threadIdx.x & 63;
    const int wave = threadIdx.x >> 6;
    const float4* xr = (const float4*)(x + (size_t)row * K_DIM);  // 1024 float4
    float m = 0.f;
    #pragma unroll
    for (int i = 0; i < 4; i++) {
        float4 v = xr[threadIdx.x + i * 256];
        m = fmaxf(m, fmaxf(fmaxf(fabsf(v.x), fabsf(v.y)), fmaxf(fabsf(v.z), fabsf(v.w))));
    }
    #pragma unroll
    for (int off = 32; off > 0; off >>= 1) m = fmaxf(m, __shfl_down(m, off, 64));
    __shared__ float wmax[4];
    if (lane == 0) wmax[wave] = m;
    __syncthreads();
    const float mx = fmaxf(fmaxf(wmax[0], wmax[1]), fmaxf(wmax[2], wmax[3]));
    const float scale = fmaxf(mx * (1.f / 127.f), 1e-30f);
    const float inv = 1.f / scale;
    if (threadIdx.x == 0) xscale[row] = scale;
    char4* oq = (char4*)(xq + (size_t)row * K_DIM);
    #pragma unroll
    for (int i = 0; i < 4; i++) {
        float4 v = xr[threadIdx.x + i * 256];  // L1/L2 hot re-read
        char4 o;
        o.x = (signed char)fminf(fmaxf(rintf(v.x * inv), -127.f), 127.f);
        o.y = (signed char)fminf(fmaxf(rintf(v.y * inv), -127.f), 127.f);
        o.z = (signed char)fminf(fmaxf(rintf(v.z * inv), -127.f), 127.f);
        o.w = (signed char)fminf(fmaxf(rintf(v.w * inv), -127.f), 127.f);
        oq[threadIdx.x + i * 256] = o;
    }
}

// ---- pass 5: C[M,N] = scale[m] * (Xq[M,K] @ Qw[N,K]^T)_i32 + bias ----
__global__ __launch_bounds__(256) void gemm_kernel(
    const char* __restrict__ xq,    // [M,K] i8
    const char* __restrict__ qw,    // [N,K] i8 ternary
    const float* __restrict__ xscale,  // [M]
    const float* __restrict__ bias,    // [N]
    float* __restrict__ out)           // [M,N] fp32
{
    __shared__ __align__(16) char As[BM * BK];  // 8 KB
    __shared__ __align__(16) char Bs[BN * BK];  // 8 KB

    const int tid  = threadIdx.x;
    const int wave = tid >> 6;
    const int lane = tid & 63;
    const int wm   = (wave >> 1) * 64;
    const int wn   = (wave & 1) * 64;
    const int lm   = lane & 15;
    const int quad = lane >> 4;

    const int bm = blockIdx.y * BM;
    const int bn = blockIdx.x * BN;

    // staging: 8 segments of 16 rows x 64 B each; wave w stages segments 2w, 2w+1
    // of A and of B. global_load_lds dest = uniform base + lane*16 -> row-major
    // [128][64] i8 when lane l covers row l/4, bytes (l%4)*16.
    const int s0    = wave * 2;
    const int srow0 = s0 * 16 + (lane >> 2);
    const int srow1 = srow0 + 16;
    const int scol  = (lane & 3) * 16;  // bytes

    const char* gA0 = xq + (size_t)(bm + srow0) * K_DIM + scol;
    const char* gA1 = xq + (size_t)(bm + srow1) * K_DIM + scol;
    const char* gB0 = qw + (size_t)(bn + srow0) * K_DIM + scol;
    const char* gB1 = qw + (size_t)(bn + srow1) * K_DIM + scol;

    char* lA0 = &As[(size_t)s0 * 1024];
    char* lA1 = &As[(size_t)(s0 + 1) * 1024];
    char* lB0 = &Bs[(size_t)s0 * 1024];
    char* lB1 = &Bs[(size_t)(s0 + 1) * 1024];

    i32x4 acc[4][4];
    #pragma unroll
    for (int i = 0; i < 4; i++)
        #pragma unroll
        for (int j = 0; j < 4; j++) acc[i][j] = (i32x4){0, 0, 0, 0};

    for (int kt = 0; kt < K_DIM; kt += BK) {
        async_copy16(gA0 + kt, lA0);
        async_copy16(gA1 + kt, lA1);
        async_copy16(gB0 + kt, lB0);
        async_copy16(gB1 + kt, lB1);
        __syncthreads();

        // A frag: m = lane&15, k-bytes = quad*16 + [0..16)  (bf16 K=32 analog, 2x K)
        i32x4 a[4], b[4];
        #pragma unroll
        for (int mi = 0; mi < 4; mi++)
            a[mi] = *(const i32x4*)&As[(wm + mi * 16 + lm) * BK + quad * 16];
        #pragma unroll
        for (int ni = 0; ni < 4; ni++)
            b[ni] = *(const i32x4*)&Bs[(wn + ni * 16 + lm) * BK + quad * 16];

        #pragma unroll
        for (int mi = 0; mi < 4; mi++)
            #pragma unroll
            for (int ni = 0; ni < 4; ni++)
                acc[mi][ni] = __builtin_amdgcn_mfma_i32_16x16x64_i8(
                    a[mi], b[ni], acc[mi][ni], 0, 0, 0);

        __syncthreads();
    }

    // epilogue: C/D layout col=lane&15, row=quad*4+reg (shape-determined, dtype-indep)
    float bl[4];
    #pragma unroll
    for (int ni = 0; ni < 4; ni++) bl[ni] = bias[bn + wn + ni * 16 + lm];

    #pragma unroll
    for (int mi = 0; mi < 4; mi++) {
        #pragma unroll
        for (int r = 0; r < 4; r++) {
            const int grow = bm + wm + mi * 16 + quad * 4 + r;
            const float sc = xscale[grow];
            float* orow = out + (size_t)grow * N_DIM + bn;
            #pragma unroll
            for (int ni = 0; ni < 4; ni++)
                orow[wn + ni * 16 + lm] = sc * (float)acc[mi][ni][r] + bl[ni];
        }
    }
}

extern "C" void kernel_launch(void* const* d_in, const int* in_sizes, int n_in,
                              void* d_out, int out_size, void* d_ws, size_t ws_size,
                              hipStream_t stream) {
    const float* x    = (const float*)d_in[0];   // [4,2048,4096] = [8192,4096]
    const float* w    = (const float*)d_in[1];   // [4096,4096]
    const float* bias = (const float*)d_in[2];   // [4096]
    float* out = (float*)d_out;

    char* ws = (char*)d_ws;
    char*   xq       = ws;                                        // 32 MB
    char*   qw       = ws + (size_t)M_DIM * K_DIM;                // 16 MB
    float*  xscale   = (float*)(qw + (size_t)N_DIM * K_DIM);      // 32 KB
    double* partials = (double*)(xscale + M_DIM);                 // 8 KB
    float*  gamma_p  = (float*)(partials + 1024);                 // 4 B

    const int wn4 = (N_DIM * K_DIM) / 4;

    abssum_partial<<<1024, 256, 0, stream>>>((const float4*)w, partials);
    gamma_reduce<<<1, 256, 0, stream>>>(partials, gamma_p);
    wquant<<<(wn4 + 255) / 256, 256, 0, stream>>>((const float4*)w, (char4*)qw, gamma_p, wn4);
    xquant<<<M_DIM, 256, 0, stream>>>(x, xq, xscale);

    dim3 grid(N_DIM / BN, M_DIM / BM);   // (32, 64)
    gemm_kernel<<<grid, 256, 0, stream>>>(xq, qw, xscale, bias, out);
}

// Round 3
// 412.021 us; speedup vs baseline: 1.4986x; 1.0410x over previous
//
#include <hip/hip_runtime.h>
#include <stdint.h>

#define M_DIM 8192
#define N_DIM 4096
#define K_DIM 4096
#define BM 128
#define BN 128
#define BK 128   // i8: 128 B/row K-slab; As+Bs = 32 KB LDS; 32 MFMA per barrier (AITER ratio)

typedef int i32x4 __attribute__((ext_vector_type(4)));

__device__ __forceinline__ void async_copy16(const void* g, void* l) {
    __builtin_amdgcn_global_load_lds(
        (const __attribute__((address_space(1))) void*)g,
        (__attribute__((address_space(3))) void*)l, 16, 0, 0);
}

// ---- pass 1: per-block partial sums of |w| (deterministic, no atomics) ----
__global__ __launch_bounds__(256) void abssum_partial(const float4* __restrict__ w,
                                                      double* __restrict__ partials) {
    const int lane = threadIdx.x & 63;
    const int wave = threadIdx.x >> 6;
    int base = blockIdx.x * 4096 + threadIdx.x;
    float s = 0.f;
    #pragma unroll
    for (int i = 0; i < 16; i++) {
        float4 v = w[base + i * 256];
        s += fabsf(v.x) + fabsf(v.y) + fabsf(v.z) + fabsf(v.w);
    }
    double d = (double)s;
    #pragma unroll
    for (int off = 32; off > 0; off >>= 1) d += __shfl_down(d, off, 64);
    __shared__ double wsum[4];
    if (lane == 0) wsum[wave] = d;
    __syncthreads();
    if (threadIdx.x == 0)
        partials[blockIdx.x] = (wsum[0] + wsum[1]) + (wsum[2] + wsum[3]);
}

// ---- pass 2: reduce 1024 partials -> gamma ----
__global__ __launch_bounds__(256) void gamma_reduce(const double* __restrict__ partials,
                                                    float* __restrict__ gamma_out) {
    const int lane = threadIdx.x & 63;
    const int wave = threadIdx.x >> 6;
    double d = partials[threadIdx.x] + partials[threadIdx.x + 256] +
               partials[threadIdx.x + 512] + partials[threadIdx.x + 768];
    #pragma unroll
    for (int off = 32; off > 0; off >>= 1) d += __shfl_down(d, off, 64);
    __shared__ double wsum[4];
    if (lane == 0) wsum[wave] = d;
    __syncthreads();
    if (threadIdx.x == 0) {
        double total = (wsum[0] + wsum[1]) + (wsum[2] + wsum[3]);
        float g = (float)(total * (1.0 / 16777216.0));  // mean |w|
        gamma_out[0] = fmaxf(g, 1e-8f);
    }
}

// ---- pass 3: quantize weight to ternary i8 ----
__global__ __launch_bounds__(256) void wquant(const float4* __restrict__ w,
                                              char4* __restrict__ qw,
                                              const float* __restrict__ gamma_p, int n4) {
    float gamma = gamma_p[0];
    int i = blockIdx.x * blockDim.x + threadIdx.x;
    if (i >= n4) return;
    float4 v = w[i];
    char4 o;
    o.x = (signed char)fminf(fmaxf(rintf(v.x / gamma), -1.f), 1.f);
    o.y = (signed char)fminf(fmaxf(rintf(v.y / gamma), -1.f), 1.f);
    o.z = (signed char)fminf(fmaxf(rintf(v.z / gamma), -1.f), 1.f);
    o.w = (signed char)fminf(fmaxf(rintf(v.w / gamma), -1.f), 1.f);
    qw[i] = o;
}

// ---- pass 4: per-row absmax + quantize x to i8 (register-resident) ----
__global__ __launch_bounds__(256) void xquant(const float4* __restrict__ x,
                                              char4* __restrict__ xq,
                                              float* __restrict__ xscale) {
    const int row = blockIdx.x;
    const int lane = threadIdx.x & 63;
    const int wave = threadIdx.x >> 6;
    const float4* xr = x + (size_t)row * (K_DIM / 4);
    float4 v[4];
    float m = 0.f;
    #pragma unroll
    for (int i = 0; i < 4; i++) {
        v[i] = xr[threadIdx.x + i * 256];
        m = fmaxf(m, fmaxf(fmaxf(fabsf(v[i].x), fabsf(v[i].y)),
                           fmaxf(fabsf(v[i].z), fabsf(v[i].w))));
    }
    #pragma unroll
    for (int off = 32; off > 0; off >>= 1) m = fmaxf(m, __shfl_down(m, off, 64));
    __shared__ float wmax[4];
    if (lane == 0) wmax[wave] = m;
    __syncthreads();
    const float mx = fmaxf(fmaxf(wmax[0], wmax[1]), fmaxf(wmax[2], wmax[3]));
    const float scale = fmaxf(mx * (1.f / 127.f), 1e-30f);
    const float inv = 1.f / scale;
    if (threadIdx.x == 0) xscale[row] = scale;
    char4* oq = xq + (size_t)row * (K_DIM / 4);
    #pragma unroll
    for (int i = 0; i < 4; i++) {
        char4 o;
        o.x = (signed char)fminf(fmaxf(rintf(v[i].x * inv), -127.f), 127.f);
        o.y = (signed char)fminf(fmaxf(rintf(v[i].y * inv), -127.f), 127.f);
        o.z = (signed char)fminf(fmaxf(rintf(v[i].z * inv), -127.f), 127.f);
        o.w = (signed char)fminf(fmaxf(rintf(v[i].w * inv), -127.f), 127.f);
        oq[threadIdx.x + i * 256] = o;
    }
}

// ---- pass 5: C[M,N] = scale[m] * (Xq[M,K] @ Qw[N,K]^T)_i32 + bias ----
// BK=128, XOR-swizzled LDS: physical chunk p = logical chunk c ^ (row&7).
// global_load_lds forces LDS dest = base + lane*16, but the SOURCE chunk per
// lane is free -> implement the swizzle on the write side by permuting source.
__global__ __launch_bounds__(256) void gemm_kernel(
    const char* __restrict__ xq,       // [M,K] i8
    const char* __restrict__ qw,       // [N,K] i8 ternary
    const float* __restrict__ xscale,  // [M]
    const float* __restrict__ bias,    // [N]
    float* __restrict__ out)           // [M,N] fp32
{
    __shared__ __align__(16) char As[BM * BK];  // 16 KB
    __shared__ __align__(16) char Bs[BN * BK];  // 16 KB

    const int tid  = threadIdx.x;
    const int wave = tid >> 6;
    const int lane = tid & 63;
    const int wm   = (wave >> 1) * 64;
    const int wn   = (wave & 1) * 64;
    const int lm   = lane & 15;
    const int quad = lane >> 4;

    const int bm = blockIdx.y * BM;
    const int bn = blockIdx.x * BN;

    // 16 segments/matrix, 1 KB each = 8 rows x 128 B. Wave stages 4 A + 4 B.
    // Lane l within segment s: LDS offset s*1024 + l*16 (hardware-forced),
    // i.e. physical (row = 8s + l/8, chunk p = l%8). Source chunk c = p ^ (row&7).
    const int sub = lane >> 3;           // row within segment
    const int ch  = (lane & 7) ^ sub;    // swizzled source chunk
    const int seg0 = wave * 4;

    const char* gA[4];
    const char* gB[4];
    #pragma unroll
    for (int i = 0; i < 4; i++) {
        const int r = (seg0 + i) * 8 + sub;
        gA[i] = xq + (size_t)(bm + r) * K_DIM + ch * 16;
        gB[i] = qw + (size_t)(bn + r) * K_DIM + ch * 16;
    }

    i32x4 acc[4][4];
    #pragma unroll
    for (int i = 0; i < 4; i++)
        #pragma unroll
        for (int j = 0; j < 4; j++) acc[i][j] = (i32x4){0, 0, 0, 0};

    for (int kt = 0; kt < K_DIM; kt += BK) {
        #pragma unroll
        for (int i = 0; i < 4; i++) {
            async_copy16(gA[i] + kt, &As[(seg0 + i) * 1024]);
            async_copy16(gB[i] + kt, &Bs[(seg0 + i) * 1024]);
        }
        __syncthreads();

        #pragma unroll
        for (int ks = 0; ks < 2; ks++) {
            // logical chunk for frag: c = ks*4 + quad; physical p = c ^ (row&7),
            // row&7 == lm&7 -> XOR spreads the quad across all 8 bank groups.
            const int p = ((ks * 4 + quad) ^ (lm & 7)) * 16;
            i32x4 a[4], b[4];
            #pragma unroll
            for (int mi = 0; mi < 4; mi++)
                a[mi] = *(const i32x4*)&As[(wm + mi * 16 + lm) * BK + p];
            #pragma unroll
            for (int ni = 0; ni < 4; ni++)
                b[ni] = *(const i32x4*)&Bs[(wn + ni * 16 + lm) * BK + p];

            #pragma unroll
            for (int mi = 0; mi < 4; mi++)
                #pragma unroll
                for (int ni = 0; ni < 4; ni++)
                    acc[mi][ni] = __builtin_amdgcn_mfma_i32_16x16x64_i8(
                        a[mi], b[ni], acc[mi][ni], 0, 0, 0);
        }
        __syncthreads();
    }

    // epilogue: C/D layout col=lane&15, row=quad*4+reg (shape-determined)
    float bl[4];
    #pragma unroll
    for (int ni = 0; ni < 4; ni++) bl[ni] = bias[bn + wn + ni * 16 + lm];

    #pragma unroll
    for (int mi = 0; mi < 4; mi++) {
        #pragma unroll
        for (int r = 0; r < 4; r++) {
            const int grow = bm + wm + mi * 16 + quad * 4 + r;
            const float sc = xscale[grow];
            float* orow = out + (size_t)grow * N_DIM + bn;
            #pragma unroll
            for (int ni = 0; ni < 4; ni++)
                orow[wn + ni * 16 + lm] = sc * (float)acc[mi][ni][r] + bl[ni];
        }
    }
}

extern "C" void kernel_launch(void* const* d_in, const int* in_sizes, int n_in,
                              void* d_out, int out_size, void* d_ws, size_t ws_size,
                              hipStream_t stream) {
    const float* x    = (const float*)d_in[0];   // [4,2048,4096] = [8192,4096]
    const float* w    = (const float*)d_in[1];   // [4096,4096]
    const float* bias = (const float*)d_in[2];   // [4096]
    float* out = (float*)d_out;

    char* ws = (char*)d_ws;
    char*   xq       = ws;                                        // 32 MB
    char*   qw       = ws + (size_t)M_DIM * K_DIM;                // 16 MB
    float*  xscale   = (float*)(qw + (size_t)N_DIM * K_DIM);      // 32 KB
    double* partials = (double*)(xscale + M_DIM);                 // 8 KB
    float*  gamma_p  = (float*)(partials + 1024);                 // 4 B

    const int wn4 = (N_DIM * K_DIM) / 4;

    abssum_partial<<<1024, 256, 0, stream>>>((const float4*)w, partials);
    gamma_reduce<<<1, 256, 0, stream>>>(partials, gamma_p);
    wquant<<<(wn4 + 255) / 256, 256, 0, stream>>>((const float4*)w, (char4*)qw, gamma_p, wn4);
    xquant<<<M_DIM, 256, 0, stream>>>((const float4*)x, (char4*)xq, xscale);

    dim3 grid(N_DIM / BN, M_DIM / BM);   // (32, 64)
    gemm_kernel<<<grid, 256, 0, stream>>>(xq, qw, xscale, bias, out);
}